// Round 10
// baseline (143.031 us; speedup 1.0000x reference)
//
#include <hip/hip_runtime.h>
#include <math.h>

// B=4, H=256, W=256, 100 iters. Closed-form mu-only update (sigma/rou are
// dead code for the mu output):
//   dmu = 2*uw1*mu + uw2*y + ew0*dn + ew1*rt + ew0_up*up + ew1_lf*lf
// Round 18: 2 Jacobi steps per barrier. r9 fit: ~0.5-0.8us/iteration of
// barrier-phase fixed cost (LDS round-trip + dep chain + barrier skew)
// dominates -> halve phase count 100 -> 53 (6 launches x 8 phases + 5).
// Per pair-phase each wave: step A on rows r0-1..r0+4 (6 rows; reads 4 mu
// + 2 v boundary rows from LDS), step B on own rows r0..r0+3 in regs, then
// writes 4 mu + 2 v rows. rowstep() expression identical to r9 -> valid
// rows bit-identical. Pair gate = need(2p+2): [18-Tl+2p, 45+Tl-2p] at
// strip granularity; step-A reads covered by 1-dilation (boundary-checked).
// v of the 2 extra rows is recomputed redundantly and discarded. mu+v
// packed float2 planes (b64, no `first` branch; init writes v=0);
// reduce_max retired (fed only dead rou). Tile 64x64, halo 16, lane=col,
// DPP laterals, Tl = 6x15+10.
#define NPIX  262144
#define TILE  64
#define TS    65             // padded LDS row stride (floats)
#define RPT   4
#define NSTRIP 16            // 16 strips x 4 rows
#define NTHR  1024
#define HALO  16

__device__ __forceinline__ float clampf(float x, float lo, float hi) {
    return fminf(fmaxf(x, lo), hi);
}
// wave-wide lateral shifts on the VALU pipe (gfx9 DPP, valid on CDNA)
__device__ __forceinline__ float dpp_shr1(float x) {   // lane l <- lane l-1
    int i = __builtin_amdgcn_update_dpp(0, __float_as_int(x),
                                        0x138, 0xf, 0xf, false);
    return __int_as_float(i);
}
__device__ __forceinline__ float dpp_shl1(float x) {   // lane l <- lane l+1
    int i = __builtin_amdgcn_update_dpp(0, __float_as_int(x),
                                        0x130, 0xf, 0xf, false);
    return __int_as_float(i);
}
// one row-update; identical expression order to r9 (bit-compatible)
__device__ __forceinline__ float rowstep(float mu_c, float up, float dn,
                                         float4 K, float K2x, float K2y,
                                         float& v) {
    float lf = dpp_shr1(mu_c);
    float rt = dpp_shl1(mu_c);
    float dmu = K.x*mu_c + K.y + K.z*dn + K.w*rt + K2x*up + K2y*lf;
    v = 0.7f*v + 0.01f*dmu;
    return clampf(mu_c + v, 0.f, 63.f);
}

// c1 = {2*uw1, uw2*y, ew0(down-edge), ew1(right-edge)}.
__global__ __launch_bounds__(NTHR) void tile_kernel(
    const float2* __restrict__ muvI, float2* __restrict__ muvO,
    const float4* __restrict__ c1,
    float* __restrict__ mu_out,   // non-null on last launch (muv not stored)
    int Tl)                       // iterations this launch (15 or 10)
{
    __shared__ float muB[2][TILE*TS];        // 33.3 KB
    __shared__ float vB[2][2*NSTRIP*TS];     // 16.6 KB (v boundary rows)

    int tid  = threadIdx.x;
    int rg   = tid >> 6;          // wave index == strip index (rows 4rg..+3)
    int lane = tid & 63;          // == tile col
    int bz = blockIdx.z;
    int h0 = blockIdx.y * 32;
    int w0 = blockIdx.x * 32;
    int w  = (w0 + lane - HALO) & 255;
    int r0 = RPT*rg;

    float mu[RPT], v[RPT];
    float4 k1[RPT], kT, kBt;
    float k2y[RPT], k2yT, k2yB, kzT2;
    int gi[RPT];

    // ---- load (fully coalesced): muv b64, c1 b128; halo-row coeffs ----
#pragma unroll
    for (int k = 0; k < RPT; ++k) {
        int h = (h0 + r0 + k - HALO) & 255;
        gi[k] = (bz << 16) | (h << 8) | w;
        float2 s = muvI[gi[k]];
        mu[k] = s.x;  v[k] = s.y;
        k1[k] = c1[gi[k]];
        k2y[k] = dpp_shr1(k1[k].w);   // left-nb ew1 (lane0: 0, garbage col)
    }
    {
        int hT  = (h0 + ((rg == 0) ? 0 : r0-1) - HALO) & 255;
        int hB  = (h0 + ((rg == NSTRIP-1) ? TILE-1 : r0+4) - HALO) & 255;
        int hT2 = (h0 + ((r0 < 2) ? 0 : r0-2) - HALO) & 255;
        kT   = c1[(bz << 16) | (hT  << 8) | w];
        kBt  = c1[(bz << 16) | (hB  << 8) | w];
        kzT2 = c1[(bz << 16) | (hT2 << 8) | w].z;
        k2yT = dpp_shr1(kT.w);
        k2yB = dpp_shr1(kBt.w);
    }
    // ---- stage all 4 mu rows (2-deep halo exchange) + v boundary rows ----
#pragma unroll
    for (int k = 0; k < RPT; ++k) muB[0][(r0+k)*TS + lane] = mu[k];
    vB[0][(2*rg)*TS + lane]   = v[0];
    vB[0][(2*rg+1)*TS + lane] = v[3];
    __syncthreads();

    int P = Tl >> 1, odd = Tl & 1;
    int rm2 = (r0 < 2) ? 0 : r0-2;
    int rm1 = (rg == 0) ? 0 : r0-1;
    int rp4 = (rg == NSTRIP-1) ? TILE-1 : r0+4;
    int rp5 = (r0+5 > TILE-1) ? TILE-1 : r0+5;
    int sT  = (rg == 0) ? 0 : 2*rg-1;                 // vTop slot
    int sB  = (rg == NSTRIP-1) ? 2*NSTRIP-1 : 2*rg+2; // vBot slot

    // ---- P pair-phases (2 steps / barrier), strip gate on need(2p+2) ----
    for (int p = 0; p < P; ++p) {
        const float* __restrict__ curM = muB[p & 1];
        float*       __restrict__ nxtM = muB[(p & 1) ^ 1];
        const float* __restrict__ curV = vB[p & 1];
        float*       __restrict__ nxtV = vB[(p & 1) ^ 1];
        int lo = 18 - Tl + 2*p, hi = 45 + Tl - 2*p;
        if (r0+3 >= lo && r0 <= hi) {     // wave-uniform
            float mT2 = curM[rm2*TS + lane];
            float mT1 = curM[rm1*TS + lane];
            float mB4 = curM[rp4*TS + lane];
            float mB5 = curM[rp5*TS + lane];
            float vT  = curV[sT*TS + lane];
            float vBo = curV[sB*TS + lane];
            // step A on 6 rows (old values only)
            float a0 = rowstep(mT1,   mT2,   mu[0], kT,    kzT2,    k2yT,   vT);
            float a1 = rowstep(mu[0], mT1,   mu[1], k1[0], kT.z,    k2y[0], v[0]);
            float a2 = rowstep(mu[1], mu[0], mu[2], k1[1], k1[0].z, k2y[1], v[1]);
            float a3 = rowstep(mu[2], mu[1], mu[3], k1[2], k1[1].z, k2y[2], v[2]);
            float a4 = rowstep(mu[3], mu[2], mB4,   k1[3], k1[2].z, k2y[3], v[3]);
            float a5 = rowstep(mB4,   mu[3], mB5,   kBt,   k1[3].z, k2yB,   vBo);
            // step B on own 4 rows (in regs)
            mu[0] = rowstep(a1, a0, a2, k1[0], kT.z,    k2y[0], v[0]);
            mu[1] = rowstep(a2, a1, a3, k1[1], k1[0].z, k2y[1], v[1]);
            mu[2] = rowstep(a3, a2, a4, k1[2], k1[1].z, k2y[2], v[2]);
            mu[3] = rowstep(a4, a3, a5, k1[3], k1[2].z, k2y[3], v[3]);
            if (p < P-1 || odd) {          // last phase feeds nobody
#pragma unroll
                for (int k = 0; k < RPT; ++k) nxtM[(r0+k)*TS + lane] = mu[k];
                nxtV[(2*rg)*TS + lane]   = v[0];
                nxtV[(2*rg+1)*TS + lane] = v[3];
            }
        }
        __syncthreads();
    }
    // ---- odd tail: one single step (always the last phase, no writes) ----
    if (odd) {
        const float* __restrict__ curM = muB[P & 1];
        if (r0 >= 16 && r0+3 <= 47) {      // gate = need(Tl) = rows [16,47]
            float mT1 = curM[rm1*TS + lane];
            float mB4 = curM[rp4*TS + lane];
            float a1 = rowstep(mu[0], mT1,   mu[1], k1[0], kT.z,    k2y[0], v[0]);
            float a2 = rowstep(mu[1], mu[0], mu[2], k1[1], k1[0].z, k2y[1], v[1]);
            float a3 = rowstep(mu[2], mu[1], mu[3], k1[2], k1[1].z, k2y[2], v[2]);
            float a4 = rowstep(mu[3], mu[2], mB4,   k1[3], k1[2].z, k2y[3], v[3]);
            mu[0] = a1; mu[1] = a2; mu[2] = a3; mu[3] = a4;
        }
    }

    // ---- store interior (rows [16,48), cols [16,48)) ----
    if (lane >= HALO && lane < HALO+32) {
#pragma unroll
        for (int k = 0; k < RPT; ++k) {
            int r = r0 + k;
            if (r >= HALO && r < HALO+32) {
                if (mu_out) {
                    mu_out[gi[k]] = mu[k];   // final launch: only mu needed
                } else {
                    muvO[gi[k]] = make_float2(mu[k], v[k]);
                }
            }
        }
    }
}

// init packed muv plane {y, 0} + invariant coefficient plane
__global__ __launch_bounds__(256) void init_state_kernel(
    const float*  __restrict__ y,
    const float2* __restrict__ ew,
    const float2* __restrict__ uw,
    float2* muvA, float4* c1)
{
    int idx = blockIdx.x*256 + threadIdx.x;
    float2 e   = ew[idx];
    float2 uwv = uw[idx];
    float  yv  = y[idx];
    muvA[idx] = make_float2(yv, 0.f);
    c1[idx]   = make_float4(2.f*uwv.x, uwv.y*yv, e.x, e.y);
}

extern "C" void kernel_launch(void* const* d_in, const int* in_sizes, int n_in,
                              void* d_out, int out_size, void* d_ws, size_t ws_size,
                              hipStream_t stream) {
    const float* y  = (const float*)d_in[0];
    const float* ew = (const float*)d_in[1];
    const float* uw = (const float*)d_in[2];
    float* out = (float*)d_out;
    const int N = NPIX;

    // workspace: c1 (float4) + muvA, muvB (float2 planes) = 8 MB
    float4* c1   = (float4*)d_ws;
    float2* muvA = (float2*)(c1 + N);
    float2* muvB = muvA + N;

    hipLaunchKernelGGL(init_state_kernel, dim3(N/256), dim3(256), 0, stream,
                       y, (const float2*)ew, (const float2*)uw, muvA, c1);

    // 6 launches of 15 iters + final launch of 10 = 100
    static const int Tls[7] = {15, 15, 15, 15, 15, 15, 10};
    float2 *muvI = muvA, *muvO = muvB;
    for (int l = 0; l < 7; ++l) {
        float* mo = (l == 6) ? out : nullptr;
        hipLaunchKernelGGL(tile_kernel, dim3(8, 8, 4), dim3(NTHR), 0, stream,
                           muvI, muvO, c1, mo, Tls[l]);
        float2* t = muvI; muvI = muvO; muvO = t;
    }
}

// Round 12
// 133.459 us; speedup vs baseline: 1.0717x; 1.0717x over previous
//
#include <hip/hip_runtime.h>
#include <math.h>

// B=4, H=256, W=256, 100 iters. Closed-form mu-only update (sigma/rou are
// dead code for the mu output):
//   dmu = 2*uw1*mu + uw2*y + ew0*dn + ew1*rt + ew0_up*up + ew1_lf*lf
// Round 20: r19 fixed. gfx950 has v_pk_{fma,mul,add}_f32 but NOT
// v_pk_{max,min}_f32 (r19 compile error) -> clamp stays scalar (4 ops/pair
// pair). Packed chain: rows packed (0,3)+(1,2), 7 pk ops + 4 scalar clamp
// per 2 rows; wave-iter VALU ~48 -> ~38 instr. Pair A = rows (0,3) = both
// LDS boundary rows: computed + written FIRST (short producer->consumer
// path); pair B pure register. Schedule {16x6,4} (col garbage after 16
// steps = [0,15]u[48,63]; stored cols [16,47] safe); last barrier of each
// launch skipped (store reads regs only). Base structure = r9 (141.1us):
// 64x64 tile, lane=col, DPP laterals, LDS only strip-boundary rows,
// strip row gate [17-Tl+s, 46+Tl-s].
#define NPIX  262144
#define TILE  64
#define TS    65             // padded LDS row stride (floats)
#define RPT   4
#define NSTRIP 16            // 16 strips x 4 rows
#define NTHR  1024
#define HALO  16

typedef float v2f __attribute__((ext_vector_type(2)));

__device__ __forceinline__ v2f pk_fma(v2f a, v2f b, v2f c) {
    v2f d;
    asm("v_pk_fma_f32 %0, %1, %2, %3" : "=v"(d) : "v"(a), "v"(b), "v"(c));
    return d;
}
__device__ __forceinline__ v2f pk_mul(v2f a, v2f b) {
    v2f d;
    asm("v_pk_mul_f32 %0, %1, %2" : "=v"(d) : "v"(a), "v"(b));
    return d;
}
__device__ __forceinline__ v2f pk_add(v2f a, v2f b) {
    v2f d;
    asm("v_pk_add_f32 %0, %1, %2" : "=v"(d) : "v"(a), "v"(b));
    return d;
}
__device__ __forceinline__ v2f pk_clamp(v2f a) {   // no pk_max/min on gfx950
    v2f d;
    d.x = fminf(fmaxf(a.x, 0.f), 63.f);
    d.y = fminf(fmaxf(a.y, 0.f), 63.f);
    return d;
}
// wave-wide lateral shifts on the VALU pipe (gfx9 DPP, valid on CDNA)
__device__ __forceinline__ float dpp_shr1(float x) {   // lane l <- lane l-1
    int i = __builtin_amdgcn_update_dpp(0, __float_as_int(x),
                                        0x138, 0xf, 0xf, false);
    return __int_as_float(i);
}
__device__ __forceinline__ float dpp_shl1(float x) {   // lane l <- lane l+1
    int i = __builtin_amdgcn_update_dpp(0, __float_as_int(x),
                                        0x130, 0xf, 0xf, false);
    return __int_as_float(i);
}

// c1 = {2*uw1, uw2*y, ew0(down-edge), ew1(right-edge)}.
__global__ __launch_bounds__(NTHR) void tile_kernel(
    const float2* __restrict__ muvI, float2* __restrict__ muvO,
    const float4* __restrict__ c1,
    float* __restrict__ mu_out,   // non-null on last launch (muv not stored)
    int Tl,                       // iterations this launch (16 or 4)
    int first)                    // launch 0: v := 0, vI not read
{
    __shared__ float buf[2][TILE*TS];   // 33.3 KB

    int tid  = threadIdx.x;
    int rg   = tid >> 6;          // wave index == strip index (rows 4rg..+3)
    int lane = tid & 63;          // == tile col
    int bz = blockIdx.z;
    int h0 = blockIdx.y * 32;
    int w0 = blockIdx.x * 32;
    int w  = (w0 + lane - HALO) & 255;
    int r0 = RPT*rg;

    float mu[RPT], v[RPT];
    float4 k1[RPT];
    int gi[RPT];

    // ---- load (fully coalesced): muv b64, c1 b128 ----
#pragma unroll
    for (int k = 0; k < RPT; ++k) {
        int h = (h0 + r0 + k - HALO) & 255;
        gi[k] = (bz << 16) | (h << 8) | w;
        float2 s = muvI[gi[k]];
        mu[k] = s.x;
        v[k]  = first ? 0.f : s.y;
        k1[k] = c1[gi[k]];
    }
    float k2x0;
    {
        int hu = (h0 + ((rg == 0) ? 0 : r0-1) - HALO) & 255;
        k2x0 = c1[(bz << 16) | (hu << 8) | w].z;   // up-nb ew0 for row 0
    }

    // ---- pack state + coefficients: pair A = rows (0,3), B = rows (1,2) ----
    v2f pmA = {mu[0], mu[3]}, pmB = {mu[1], mu[2]};
    v2f pvA = {v[0],  v[3]},  pvB = {v[1],  v[2]};
    v2f KxA = {k1[0].x, k1[3].x}, KxB = {k1[1].x, k1[2].x};
    v2f KyA = {k1[0].y, k1[3].y}, KyB = {k1[1].y, k1[2].y};
    v2f KzA = {k1[0].z, k1[3].z}, KzB = {k1[1].z, k1[2].z};
    v2f KwA = {k1[0].w, k1[3].w}, KwB = {k1[1].w, k1[2].w};
    v2f K2xA = {k2x0,    k1[2].z}, K2xB = {k1[0].z, k1[1].z};
    v2f K2yA = {dpp_shr1(k1[0].w), dpp_shr1(k1[3].w)};
    v2f K2yB = {dpp_shr1(k1[1].w), dpp_shr1(k1[2].w)};
    const v2f C07  = {0.7f, 0.7f};
    const v2f C001 = {0.01f, 0.01f};

    // stage only strip-boundary rows (the only LDS-read rows)
    buf[0][r0*TS + lane]       = pmA.x;
    buf[0][(r0 + 3)*TS + lane] = pmA.y;
    __syncthreads();

    int rm1 = (rg == 0)        ? 0      : r0-1;
    int rp4 = (rg == NSTRIP-1) ? TILE-1 : r0+4;

    // ---- Tl fused Jacobi iterations, one barrier each, strip row gate ----
    for (int s = 0; s < Tl; ++s) {
        const float* __restrict__ cur = buf[s & 1];
        float*       __restrict__ nxt = buf[(s & 1) ^ 1];
        // useful rows [17-Tl+s, 46+Tl-s]; strip granular
        int lo = 14 - Tl + s;                    // 4rg >= lo
        int rgLo = (lo <= 0) ? 0 : ((lo + 3) >> 2);
        int rgHi = (46 + Tl - s) >> 2;           // <= 15 for Tl<=16
        if (rg >= rgLo && rg <= rgHi) {          // wave-uniform branch
            float up0 = cur[rm1*TS + lane];
            float dnL = cur[rp4*TS + lane];
            // pair A (rows 0,3): produces next phase's boundary rows
            v2f upA = {up0,   pmB.y};            // {up(row0), mu2}
            v2f dnA = {pmB.x, dnL};              // {mu1, dn(row3)}
            v2f lfA = {dpp_shr1(pmA.x), dpp_shr1(pmA.y)};
            v2f rtA = {dpp_shl1(pmA.x), dpp_shl1(pmA.y)};
            v2f d = pk_fma(KxA, pmA, KyA);
            d = pk_fma(KzA, dnA, d);
            d = pk_fma(KwA, rtA, d);
            d = pk_fma(K2xA, upA, d);
            d = pk_fma(K2yA, lfA, d);
            pvA = pk_fma(pvA, C07, pk_mul(C001, d));
            v2f nmA = pk_clamp(pk_add(pmA, pvA));
            nxt[r0*TS + lane]       = nmA.x;     // boundary rows out ASAP
            nxt[(r0 + 3)*TS + lane] = nmA.y;
            // pair B (rows 1,2): pure register (old pmA/pmB still live)
            v2f upB = {pmA.x, pmB.x};            // {mu0, mu1}
            v2f dnB = {pmB.y, pmA.y};            // {mu2, mu3}
            v2f lfB = {dpp_shr1(pmB.x), dpp_shr1(pmB.y)};
            v2f rtB = {dpp_shl1(pmB.x), dpp_shl1(pmB.y)};
            v2f e = pk_fma(KxB, pmB, KyB);
            e = pk_fma(KzB, dnB, e);
            e = pk_fma(KwB, rtB, e);
            e = pk_fma(K2xB, upB, e);
            e = pk_fma(K2yB, lfB, e);
            pvB = pk_fma(pvB, C07, pk_mul(C001, e));
            v2f nmB = pk_clamp(pk_add(pmB, pvB));
            pmA = nmA;
            pmB = nmB;
        }
        if (s + 1 < Tl) __syncthreads();   // last phase feeds registers only
    }

    // ---- store interior (rows [16,48), cols [16,48)) ----
    if (lane >= HALO && lane < HALO+32) {
        float muO[RPT] = {pmA.x, pmB.x, pmB.y, pmA.y};
        float vO_[RPT] = {pvA.x, pvB.x, pvB.y, pvA.y};
#pragma unroll
        for (int k = 0; k < RPT; ++k) {
            int r = r0 + k;
            if (r >= HALO && r < HALO+32) {
                if (mu_out) {
                    mu_out[gi[k]] = muO[k];  // final launch: only mu needed
                } else {
                    muvO[gi[k]] = make_float2(muO[k], vO_[k]);
                }
            }
        }
    }
}

// init packed muv plane {y, 0} + invariant coefficient plane
__global__ __launch_bounds__(256) void init_state_kernel(
    const float*  __restrict__ y,
    const float2* __restrict__ ew,
    const float2* __restrict__ uw,
    float2* muvA, float4* c1)
{
    int idx = blockIdx.x*256 + threadIdx.x;
    float2 e   = ew[idx];
    float2 uwv = uw[idx];
    float  yv  = y[idx];
    muvA[idx] = make_float2(yv, 0.f);
    c1[idx]   = make_float4(2.f*uwv.x, uwv.y*yv, e.x, e.y);
}

extern "C" void kernel_launch(void* const* d_in, const int* in_sizes, int n_in,
                              void* d_out, int out_size, void* d_ws, size_t ws_size,
                              hipStream_t stream) {
    const float* y  = (const float*)d_in[0];
    const float* ew = (const float*)d_in[1];
    const float* uw = (const float*)d_in[2];
    float* out = (float*)d_out;
    const int N = NPIX;

    // workspace: c1 (float4) + muvA, muvB (float2 planes) = 8 MB
    float4* c1   = (float4*)d_ws;
    float2* muvA = (float2*)(c1 + N);
    float2* muvB = muvA + N;

    hipLaunchKernelGGL(init_state_kernel, dim3(N/256), dim3(256), 0, stream,
                       y, (const float2*)ew, (const float2*)uw, muvA, c1);

    // 6 launches of 16 iters + final launch of 4 = 100
    static const int Tls[7] = {16, 16, 16, 16, 16, 16, 4};
    float2 *muvI = muvA, *muvO = muvB;
    for (int l = 0; l < 7; ++l) {
        float* mo = (l == 6) ? out : nullptr;
        hipLaunchKernelGGL(tile_kernel, dim3(8, 8, 4), dim3(NTHR), 0, stream,
                           muvI, muvO, c1, mo, Tls[l], (l == 0) ? 1 : 0);
        float2* t = muvI; muvI = muvO; muvO = t;
    }
}